// Round 9
// baseline (792.718 us; speedup 1.0000x reference)
//
#include <hip/hip_runtime.h>

typedef float  f4  __attribute__((ext_vector_type(4)));
typedef float  v4f __attribute__((ext_vector_type(4)));
typedef __bf16 v8bf __attribute__((ext_vector_type(8)));
typedef unsigned short us4 __attribute__((ext_vector_type(4)));
typedef unsigned short us8 __attribute__((ext_vector_type(8)));

#define DI __device__ __forceinline__

DI unsigned short f2b(float f) {
    unsigned u = __builtin_bit_cast(unsigned, f);
    u += 0x7fffu + ((u >> 16) & 1u);           // RNE
    return (unsigned short)(u >> 16);
}
DI float b2f(unsigned short s) {
    unsigned u = ((unsigned)s) << 16;
    return __builtin_bit_cast(float, u);
}

// ---------------- weight conversion ----------------

__global__ void cvt_kernel(const float* __restrict__ s, unsigned short* __restrict__ d, int n4) {
    int i = blockIdx.x * 256 + threadIdx.x;
    if (i < n4) {
        f4 v = *(const f4*)(s + (size_t)i * 4);
        us4 o;
        #pragma unroll
        for (int j = 0; j < 4; ++j) o[j] = f2b(v[j]);
        *(us4*)(d + (size_t)i * 4) = o;
    }
}

// Wq/Wk/Wv (H,C,64) fp32 -> Wqkv bf16 [n=which*1024+h*64+d][c]  (B^T layout)
__global__ void cvt_qkv(const float* __restrict__ Wq, const float* __restrict__ Wk,
                        const float* __restrict__ Wv, unsigned short* __restrict__ Wqkv) {
    int c0 = blockIdx.x * 64, h = blockIdx.y, which = blockIdx.z;
    const float* W = (which == 0) ? Wq : (which == 1) ? Wk : Wv;
    const float* src = W + ((size_t)h * 1024 + c0) * 64;
    __shared__ float tile[64][65];
    int t = threadIdx.x;
    #pragma unroll
    for (int rep = 0; rep < 4; ++rep) {
        int f = (rep * 256 + t) * 4;
        int ci = f >> 6, d = f & 63;
        f4 v = *(const f4*)(src + ci * 64 + d);
        tile[ci][d] = v[0]; tile[ci][d + 1] = v[1]; tile[ci][d + 2] = v[2]; tile[ci][d + 3] = v[3];
    }
    __syncthreads();
    #pragma unroll
    for (int rep = 0; rep < 4; ++rep) {
        int g = rep * 256 + t;
        int d = g >> 4, cq = (g & 15) * 4;
        int n = which * 1024 + h * 64 + d;
        us4 o;
        o[0] = f2b(tile[cq][d]); o[1] = f2b(tile[cq + 1][d]);
        o[2] = f2b(tile[cq + 2][d]); o[3] = f2b(tile[cq + 3][d]);
        *(us4*)(Wqkv + (size_t)n * 1024 + c0 + cq) = o;
    }
}

// ---------------- layernorm (f32 in -> bf16 out) ----------------

__global__ __launch_bounds__(256) void ln_kernel(const float* __restrict__ x,
                                                 const float* __restrict__ w,
                                                 unsigned short* __restrict__ o) {
    int row = blockIdx.x, t = threadIdx.x;
    const float* xr = x + (size_t)row * 1024;
    f4 v = *(const f4*)(xr + t * 4);
    float s  = v[0] + v[1] + v[2] + v[3];
    float s2 = v[0]*v[0] + v[1]*v[1] + v[2]*v[2] + v[3]*v[3];
    #pragma unroll
    for (int off = 1; off < 64; off <<= 1) {
        s  += __shfl_xor(s, off, 64);
        s2 += __shfl_xor(s2, off, 64);
    }
    __shared__ float red[8];
    int wv = t >> 6, ln = t & 63;
    if (ln == 0) { red[wv] = s; red[4 + wv] = s2; }
    __syncthreads();
    s  = red[0] + red[1] + red[2] + red[3];
    s2 = red[4] + red[5] + red[6] + red[7];
    float mu  = s * (1.f / 1024.f);
    float var = s2 * (1.f / 1024.f) - mu * mu;
    float rr  = rsqrtf(var + 1e-5f);
    f4 wv4 = *(const f4*)(w + t * 4);
    us4 ov;
    #pragma unroll
    for (int j = 0; j < 4; ++j) ov[j] = f2b((v[j] - mu) * rr * wv4[j]);
    *(us4*)(o + (size_t)row * 1024 + t * 4) = ov;
}

// ---------------- GEMM (A: MxK row-major bf16, B: NxK row-major bf16) ----------------
// 128x128 tile, BK=64, 4 waves (2x2), each wave 64x64 via 4x4 of 16x16x32 MFMA.
// Staging: global->reg (prefetch next tile) -> ds_write. LDS: [kchunk 8][row 128][16B].
// EPI: 0=QKV(+bias, scatter q/k/vT), 1=oproj(+x resid -> f32 XA), 2=gelu->bf16 FF1,
//      3=ff2(+XA resid -> X3 bf16; tail rows -> f32 out)

template<int EPI>
__global__ __launch_bounds__(256) void gemm_bt(
    const unsigned short* __restrict__ A, const unsigned short* __restrict__ B, int K,
    const float* __restrict__ ef0, const float* __restrict__ ef1, const float* __restrict__ ef2,
    unsigned short* __restrict__ ob0, unsigned short* __restrict__ ob1, unsigned short* __restrict__ ob2,
    float* __restrict__ of0) {
    __shared__ __align__(16) char As[16384];
    __shared__ __align__(16) char Bs[16384];
    int tid = threadIdx.x, lane = tid & 63, w = tid >> 6;
    int wm = w >> 1, wn = w & 1;
    int tn = blockIdx.x, tm = blockIdx.y;
    int lm = lane & 15, lg = lane >> 4;
    int rowA = tm * 128, colB = tn * 128;
    int srow = tid >> 3, skc = tid & 7;
    const unsigned short* Ap = A + (size_t)(rowA + srow) * K + skc * 8;
    const unsigned short* Bp = B + (size_t)(colB + srow) * K + skc * 8;
    us8 ra[4], rb[4];
    #pragma unroll
    for (int i = 0; i < 4; ++i) {
        ra[i] = *(const us8*)(Ap + (size_t)(i * 32) * K);
        rb[i] = *(const us8*)(Bp + (size_t)(i * 32) * K);
    }
    v4f acc[4][4] = {};
    int nk = K >> 6;
    for (int t = 0; t < nk; ++t) {
        __syncthreads();
        #pragma unroll
        for (int i = 0; i < 4; ++i) {
            *(us8*)(As + skc * 2048 + (i * 32 + srow) * 16) = ra[i];
            *(us8*)(Bs + skc * 2048 + (i * 32 + srow) * 16) = rb[i];
        }
        __syncthreads();
        if (t + 1 < nk) {
            int k0 = (t + 1) * 64;
            #pragma unroll
            for (int i = 0; i < 4; ++i) {
                ra[i] = *(const us8*)(Ap + (size_t)(i * 32) * K + k0);
                rb[i] = *(const us8*)(Bp + (size_t)(i * 32) * K + k0);
            }
        }
        #pragma unroll
        for (int kk = 0; kk < 2; ++kk) {
            v8bf a[4], b[4];
            #pragma unroll
            for (int mi = 0; mi < 4; ++mi)
                a[mi] = *(const v8bf*)(As + (kk*4 + lg) * 2048 + (wm*64 + mi*16 + lm) * 16);
            #pragma unroll
            for (int ni = 0; ni < 4; ++ni)
                b[ni] = *(const v8bf*)(Bs + (kk*4 + lg) * 2048 + (wn*64 + ni*16 + lm) * 16);
            #pragma unroll
            for (int mi = 0; mi < 4; ++mi)
                #pragma unroll
                for (int ni = 0; ni < 4; ++ni)
                    acc[mi][ni] = __builtin_amdgcn_mfma_f32_16x16x32_bf16(a[mi], b[ni], acc[mi][ni], 0, 0, 0);
        }
    }
    int mbase = tm * 128 + wm * 64;
    int nbase = tn * 128 + wn * 64;
    #pragma unroll
    for (int mi = 0; mi < 4; ++mi)
    #pragma unroll
    for (int ni = 0; ni < 4; ++ni)
    #pragma unroll
    for (int r = 0; r < 4; ++r) {
        int row = mbase + mi * 16 + lg * 4 + r;
        int col = nbase + ni * 16 + lm;
        float v = acc[mi][ni][r];
        if constexpr (EPI == 0) {
            int which = col >> 10, hc = col & 1023;
            int hh = hc >> 6, d = hc & 63;
            const float* bp = (which == 0) ? ef0 : (which == 1) ? ef1 : ef2;
            v += bp[hh * 64 + d];
            int bb = row >> 11, t = row & 2047;
            int bh = bb * 16 + hh;
            if (which == 0)      ob0[((size_t)bh * 2048 + t) * 64 + d] = f2b(v * 0.03125f);
            else if (which == 1) ob1[((size_t)bh * 2048 + t) * 64 + d] = f2b(v);
            else                 ob2[((size_t)bh * 64 + d) * 2048 + t] = f2b(v);  // V^T
        } else if constexpr (EPI == 1) {
            v += ef0[(size_t)row * 1024 + col];
            of0[(size_t)row * 1024 + col] = v;
        } else if constexpr (EPI == 2) {
            float g = 0.5f * v * (1.f + erff(v * 0.70710678118f));
            ob0[(size_t)row * 4096 + col] = f2b(g);
        } else {                                  // FF2 + XA resid
            v += ef0[(size_t)row * 1024 + col];
            ob1[(size_t)row * 1024 + col] = f2b(v);   // X3 bf16 (for fades)
            int t = row & 2047;
            if (t >= 1536) {                          // x4 tail -> f32 out
                int bb = row >> 11;
                of0[((size_t)bb * 1024 + (t - 1024)) * 1024 + col] = v;
            }
        }
    }
}

// ---------------- flash attention (causal), MFMA ----------------
// Q,K: [bh][t][64] bf16 (q pre-scaled 1/32); VT: [bh][d][t] bf16; O: [b][t][h*64+d] bf16
// 4 waves, 128 q-rows/block (32/wave), kv tiles of 64. Reg-staged K/V with prefetch.

__global__ __launch_bounds__(256) void attn_kernel(
    const unsigned short* __restrict__ Q, const unsigned short* __restrict__ Kb,
    const unsigned short* __restrict__ VT, unsigned short* __restrict__ O) {
    __shared__ __align__(16) char kls[8192];                 // [dc 8][kv 64][16B]
    __shared__ __align__(16) char vls[8192];                 // [kvc 8][d 64][16B]
    __shared__ __align__(16) unsigned short pls[4][2048];    // per-wave P: [kvc 8][q 32][8]
    int tid = threadIdx.x, lane = tid & 63, w = tid >> 6;
    int lm = lane & 15, lg = lane >> 4;
    int qt = blockIdx.x & 15, bh = blockIdx.x >> 4;
    int q0 = qt * 128;
    const unsigned short* qp = Q  + (size_t)bh * 2048 * 64;
    const unsigned short* kp = Kb + (size_t)bh * 2048 * 64;
    const unsigned short* vp = VT + (size_t)bh * 64 * 2048;
    int sr = tid >> 3, sc = tid & 7;

    v8bf aq[2][2];
    #pragma unroll
    for (int mi = 0; mi < 2; ++mi)
        #pragma unroll
        for (int kk = 0; kk < 2; ++kk)
            aq[mi][kk] = *(const v8bf*)(qp + (size_t)(q0 + w*32 + mi*16 + lm) * 64 + kk*32 + lg*8);

    us8 rk[2], rv[2];
    #pragma unroll
    for (int i = 0; i < 2; ++i) {
        rk[i] = *(const us8*)(kp + (size_t)(i*32 + sr) * 64 + sc * 8);
        rv[i] = *(const us8*)(vp + (size_t)(i*32 + sr) * 2048 + sc * 8);
    }

    v4f oacc[2][4] = {};
    float mrun[2][4], lrun[2][4];
    #pragma unroll
    for (int mi = 0; mi < 2; ++mi)
        #pragma unroll
        for (int r = 0; r < 4; ++r) { mrun[mi][r] = -3.0e38f; lrun[mi][r] = 0.f; }

    for (int kv0 = 0; kv0 < q0 + 128; kv0 += 64) {
        __syncthreads();
        #pragma unroll
        for (int i = 0; i < 2; ++i) {
            *(us8*)(kls + sc * 1024 + (i*32 + sr) * 16) = rk[i];
            *(us8*)(vls + sc * 1024 + (i*32 + sr) * 16) = rv[i];
        }
        __syncthreads();
        if (kv0 + 64 < q0 + 128) {
            int nx = kv0 + 64;
            #pragma unroll
            for (int i = 0; i < 2; ++i) {
                rk[i] = *(const us8*)(kp + (size_t)(nx + i*32 + sr) * 64 + sc * 8);
                rv[i] = *(const us8*)(vp + (size_t)(i*32 + sr) * 2048 + nx + sc * 8);
            }
        }
        // S = Q K^T
        v4f s[2][4] = {};
        #pragma unroll
        for (int kk = 0; kk < 2; ++kk) {
            v8bf bk[4];
            #pragma unroll
            for (int ni = 0; ni < 4; ++ni)
                bk[ni] = *(const v8bf*)(kls + (kk*4 + lg) * 1024 + (ni*16 + lm) * 16);
            #pragma unroll
            for (int mi = 0; mi < 2; ++mi)
                #pragma unroll
                for (int ni = 0; ni < 4; ++ni)
                    s[mi][ni] = __builtin_amdgcn_mfma_f32_16x16x32_bf16(aq[mi][kk], bk[ni], s[mi][ni], 0, 0, 0);
        }
        if (kv0 + 63 > q0) {
            #pragma unroll
            for (int mi = 0; mi < 2; ++mi)
                #pragma unroll
                for (int ni = 0; ni < 4; ++ni)
                    #pragma unroll
                    for (int r = 0; r < 4; ++r) {
                        int qrow = q0 + w*32 + mi*16 + lg*4 + r;
                        int kvg  = kv0 + ni*16 + lm;
                        if (kvg > qrow) s[mi][ni][r] = -1e30f;
                    }
        }
        #pragma unroll
        for (int mi = 0; mi < 2; ++mi) {
            float mx[4], ps[4];
            #pragma unroll
            for (int r = 0; r < 4; ++r)
                mx[r] = fmaxf(fmaxf(s[mi][0][r], s[mi][1][r]), fmaxf(s[mi][2][r], s[mi][3][r]));
            #pragma unroll
            for (int off = 1; off <= 8; off <<= 1)
                #pragma unroll
                for (int r = 0; r < 4; ++r)
                    mx[r] = fmaxf(mx[r], __shfl_xor(mx[r], off, 64));
            #pragma unroll
            for (int r = 0; r < 4; ++r) {
                float mnew  = fmaxf(mrun[mi][r], mx[r]);
                float alpha = __expf(mrun[mi][r] - mnew);
                mrun[mi][r] = mnew;
                lrun[mi][r] *= alpha;
                #pragma unroll
                for (int nd = 0; nd < 4; ++nd) oacc[mi][nd][r] *= alpha;
            }
            #pragma unroll
            for (int ni = 0; ni < 4; ++ni)
                #pragma unroll
                for (int r = 0; r < 4; ++r)
                    s[mi][ni][r] = __expf(s[mi][ni][r] - mrun[mi][r]);
            #pragma unroll
            for (int r = 0; r < 4; ++r)
                ps[r] = s[mi][0][r] + s[mi][1][r] + s[mi][2][r] + s[mi][3][r];
            #pragma unroll
            for (int off = 1; off <= 8; off <<= 1)
                #pragma unroll
                for (int r = 0; r < 4; ++r)
                    ps[r] += __shfl_xor(ps[r], off, 64);
            #pragma unroll
            for (int r = 0; r < 4; ++r) lrun[mi][r] += ps[r];
            #pragma unroll
            for (int ni = 0; ni < 4; ++ni)
                #pragma unroll
                for (int r = 0; r < 4; ++r) {
                    int qL  = mi*16 + lg*4 + r;
                    int kvL = ni*16 + lm;
                    pls[w][(kvL >> 3) * 256 + qL * 8 + (kvL & 7)] = f2b(s[mi][ni][r]);
                }
        }
        // O += P V  (in-wave DS ordering: write then read of pls[w])
        #pragma unroll
        for (int kk = 0; kk < 2; ++kk) {
            v8bf ap[2], bv2[4];
            #pragma unroll
            for (int mi = 0; mi < 2; ++mi)
                ap[mi] = *(const v8bf*)(&pls[w][(kk*4 + lg) * 256 + (mi*16 + lm) * 8]);
            #pragma unroll
            for (int nd = 0; nd < 4; ++nd)
                bv2[nd] = *(const v8bf*)(vls + (kk*4 + lg) * 1024 + (nd*16 + lm) * 16);
            #pragma unroll
            for (int mi = 0; mi < 2; ++mi)
                #pragma unroll
                for (int nd = 0; nd < 4; ++nd)
                    oacc[mi][nd] = __builtin_amdgcn_mfma_f32_16x16x32_bf16(ap[mi], bv2[nd], oacc[mi][nd], 0, 0, 0);
        }
    }
    int bb = bh >> 4, h = bh & 15;
    #pragma unroll
    for (int mi = 0; mi < 2; ++mi)
        #pragma unroll
        for (int nd = 0; nd < 4; ++nd)
            #pragma unroll
            for (int r = 0; r < 4; ++r) {
                int t = q0 + w*32 + mi*16 + lg*4 + r;
                int c = h*64 + nd*16 + lm;
                O[((size_t)bb * 2048 + t) * 1024 + c] = f2b(oacc[mi][nd][r] / lrun[mi][r]);
            }
}

// ---------------- fading heads: y[b,n,c] = sum_t fW[n,t] * x3[b,t0+t,c]  -> f32 out ----------------

__global__ __launch_bounds__(256) void fade_kernel(const unsigned short* __restrict__ x3,
                                                   const float* __restrict__ fw,
                                                   float* __restrict__ out,
                                                   int K, int t0, int row0) {
    int b = blockIdx.z, n0 = blockIdx.y * 16, c = blockIdx.x * 256 + threadIdx.x;
    __shared__ float fwl[16][64];
    float acc[16];
    #pragma unroll
    for (int i = 0; i < 16; ++i) acc[i] = 0.f;
    for (int tc = 0; tc < K; tc += 64) {
        int f = threadIdx.x * 4;
        int ni = f >> 6, tt = f & 63;
        *(f4*)&fwl[ni][tt] = *(const f4*)&fw[(size_t)(n0 + ni) * K + tc + tt];
        __syncthreads();
        for (int t = 0; t < 64; ++t) {
            float v = b2f(x3[((size_t)b * 2048 + t0 + tc + t) * 1024 + c]);
            #pragma unroll
            for (int i = 0; i < 16; ++i) acc[i] += fwl[i][t] * v;
        }
        __syncthreads();
    }
    #pragma unroll
    for (int i = 0; i < 16; ++i)
        out[((size_t)b * 1024 + row0 + n0 + i) * 1024 + c] = acc[i];
}

// ---------------- launch ----------------
// ws layout (MB): 0-6 WQKV | 6-8 WOB | 8-16 W1B (later X3) | 16-24 H1 | 24-32 QB |
// 32-40 KB2 | 40-48 VTB | 48-56 OB | 24-56 FF1 (after attn/oproj) | 56-72 XA f32 |
// 0-8 W2B (after oproj). Peak = 72 MB.  d_out: float32, 2M elements.

extern "C" void kernel_launch(void* const* d_in, const int* in_sizes, int n_in,
                              void* d_out, int out_size, void* d_ws, size_t ws_size,
                              hipStream_t stream) {
    (void)in_sizes; (void)n_in; (void)out_size; (void)ws_size;
    const float* x    = (const float*)d_in[0];
    const float* ln1w = (const float*)d_in[1];
    const float* Wq   = (const float*)d_in[2];
    const float* bq   = (const float*)d_in[3];
    const float* Wk   = (const float*)d_in[4];
    const float* bk   = (const float*)d_in[5];
    const float* Wv   = (const float*)d_in[6];
    const float* bv   = (const float*)d_in[7];
    const float* Wo   = (const float*)d_in[8];
    const float* ln2w = (const float*)d_in[9];
    const float* W1   = (const float*)d_in[10];
    const float* W2   = (const float*)d_in[11];
    const float* fW1  = (const float*)d_in[12];
    const float* fW2  = (const float*)d_in[13];
    const float* fW3  = (const float*)d_in[14];
    float* out = (float*)d_out;                              // fp32 output!
    char* ws = (char*)d_ws;
    const size_t MB = 1024 * 1024;

    unsigned short* WQKV = (unsigned short*)(ws + 0);
    unsigned short* WOB  = (unsigned short*)(ws + 6 * MB);
    unsigned short* W1B  = (unsigned short*)(ws + 8 * MB);
    unsigned short* H1   = (unsigned short*)(ws + 16 * MB);
    unsigned short* QB   = (unsigned short*)(ws + 24 * MB);
    unsigned short* KB2  = (unsigned short*)(ws + 32 * MB);
    unsigned short* VTB  = (unsigned short*)(ws + 40 * MB);
    unsigned short* OB   = (unsigned short*)(ws + 48 * MB);
    float*          XA   = (float*)(ws + 56 * MB);
    unsigned short* W2B  = (unsigned short*)(ws + 0);
    unsigned short* FF1  = (unsigned short*)(ws + 24 * MB);
    unsigned short* X3   = (unsigned short*)(ws + 8 * MB);

    cvt_qkv<<<dim3(16, 16, 3), 256, 0, stream>>>(Wq, Wk, Wv, WQKV);
    cvt_kernel<<<1024, 256, 0, stream>>>(Wo, WOB, 262144);
    cvt_kernel<<<4096, 256, 0, stream>>>(W1, W1B, 1048576);
    ln_kernel<<<4096, 256, 0, stream>>>(x, ln1w, H1);
    gemm_bt<0><<<dim3(24, 32), 256, 0, stream>>>(H1, WQKV, 1024,
                                                 bq, bk, bv, QB, KB2, VTB, nullptr);
    attn_kernel<<<512, 256, 0, stream>>>(QB, KB2, VTB, OB);
    gemm_bt<1><<<dim3(8, 32), 256, 0, stream>>>(OB, WOB, 1024,
                                                x, nullptr, nullptr, nullptr, nullptr, nullptr, XA);
    cvt_kernel<<<4096, 256, 0, stream>>>(W2, W2B, 1048576);
    ln_kernel<<<4096, 256, 0, stream>>>(XA, ln2w, H1);
    gemm_bt<2><<<dim3(32, 32), 256, 0, stream>>>(H1, W1B, 1024,
                                                 nullptr, nullptr, nullptr, FF1, nullptr, nullptr, nullptr);
    gemm_bt<3><<<dim3(8, 32), 256, 0, stream>>>(FF1, W2B, 4096,
                                                XA, nullptr, nullptr, nullptr, X3, nullptr, out);
    fade_kernel<<<dim3(4, 8, 2), 256, 0, stream>>>(X3, fW1, out, 768, 0, 0);
    fade_kernel<<<dim3(4, 8, 2), 256, 0, stream>>>(X3, fW2, out, 384, 768, 128);
    fade_kernel<<<dim3(4, 16, 2), 256, 0, stream>>>(X3, fW3, out, 384, 1152, 256);
}